// Round 15
// baseline (460.418 us; speedup 1.0000x reference)
//
#include <hip/hip_runtime.h>

typedef __attribute__((ext_vector_type(8))) short bf16x8;
typedef __attribute__((ext_vector_type(4))) float f32x4;
typedef __attribute__((ext_vector_type(4))) unsigned short us4;
typedef __attribute__((ext_vector_type(8))) unsigned short us8;

#define NROWS 262144
#define KC 256
#define DD 256
#define BM 128       // rows per block (8 steps x 16 rows)
#define DK 32        // D-chunk (= one MFMA K)
#define TAU 1.5e-3f  // flag threshold: ~9 sigma of single-pass bf16 error + np fp32 rounding
#define FCAP 65536   // flag list capacity

// ===== bit-exact numpy emulation helpers (defeat -ffp-contract) =====
__device__ __forceinline__ float np_pw128_sq(const float* a) {
    float r[8];
#pragma unroll
    for (int j = 0; j < 8; ++j) r[j] = __fmul_rn(a[j], a[j]);
    for (int i = 8; i < 128; i += 8) {
#pragma unroll
        for (int j = 0; j < 8; ++j)
            r[j] = __fadd_rn(r[j], __fmul_rn(a[i + j], a[i + j]));
    }
    float t01 = __fadd_rn(r[0], r[1]), t23 = __fadd_rn(r[2], r[3]);
    float t45 = __fadd_rn(r[4], r[5]), t67 = __fadd_rn(r[6], r[7]);
    return __fadd_rn(__fadd_rn(t01, t23), __fadd_rn(t45, t67));
}
__device__ __forceinline__ float np_sum256_sq(const float* a) {
    return __fadd_rn(np_pw128_sq(a), np_pw128_sq(a + 128));
}

// bf16 round-to-nearest-even
__device__ __forceinline__ unsigned short bf16_rne(float x) {
    unsigned b = __float_as_uint(x);
    b += 0x7FFFu + ((b >> 16) & 1u);
    return (unsigned short)(b >> 16);
}

// ---------- prep: se[k] = np-bit-exact sum(emb[k]^2); zero accum + flag count ----------
__global__ void vq_prep(const float* __restrict__ emb, float* __restrict__ se,
                        double* __restrict__ accum, int* __restrict__ gcnt) {
    int k = threadIdx.x;
    if (k == 0) { *accum = 0.0; *gcnt = 0; }
    se[k] = np_sum256_sq(emb + (size_t)k * DD);
}

// ---------- split emb -> dc-tiled bf16 (RNE) plane: plane[tile][k][32] ----------
__global__ void vq_split(const float* __restrict__ emb, unsigned short* __restrict__ ph) {
    int f = (blockIdx.x * 256 + threadIdx.x) * 4;   // element index
    float4 v = *reinterpret_cast<const float4*>(emb + f);
    int k = f >> 8, d = f & 255;
    int off = (d >> 5) * (KC * DK) + k * DK + (d & 31);
    us4 h;
    h[0] = bf16_rne(v.x); h[1] = bf16_rne(v.y);
    h[2] = bf16_rne(v.z); h[3] = bf16_rne(v.w);
    *reinterpret_cast<us4*>(ph + off) = h;
}

// ---------- main: TRANSPOSED MFMA (codes=A persistent, z=B). Lane-local argmin. ----------
__global__ __launch_bounds__(256, 2)
void vq_main(const float* __restrict__ ze, const unsigned short* __restrict__ ph,
             const float* __restrict__ se_g, float* __restrict__ out_inds,
             double* __restrict__ accum, int* __restrict__ glist, int* __restrict__ gcnt)
{
    __shared__ float wv1[4 * BM], wv2[4 * BM];   // per-wave slices, no in-loop sync
    __shared__ int   wk1[4 * BM];
    __shared__ float red[256];

    const int t = threadIdx.x;
    const int w = t >> 6;          // wave: codes [64w, 64w+64)
    const int q = (t >> 4) & 3;    // k-quad within frag
    const int c = t & 15;          // A code-row / B z-col within frag
    const size_t m0 = (size_t)blockIdx.x * BM;

    // ---- persistent code A-frags: wave's 64 codes x 256 d (same bytes as old B-frags) ----
    bf16x8 cfr[4][8];   // [mf][dci]
#pragma unroll
    for (int mf = 0; mf < 4; ++mf)
#pragma unroll
        for (int dci = 0; dci < 8; ++dci)
            cfr[mf][dci] = *reinterpret_cast<const bf16x8*>(
                ph + dci * (KC * DK) + (w * 64 + mf * 16 + c) * DK + q * 8);

    // ---- this lane's 16 se values: code = 64w + 16mf + 4q + j (L2-hot, 1 txn/instr) ----
    float se_v[4][4];
#pragma unroll
    for (int mf = 0; mf < 4; ++mf)
#pragma unroll
        for (int j = 0; j < 4; ++j)
            se_v[mf][j] = se_g[64 * w + 16 * mf + 4 * q + j];

    float sz_run = 0.f;

    // ---- prologue: z loads for step 0 (lane (c,q): row c, d-slice q*8 of each dci) ----
    float4 z0[8], z1[8];
    {
        const float* zb = ze + (m0 + c) * DD + q * 8;
#pragma unroll
        for (int dci = 0; dci < 8; ++dci) {
            z0[dci] = *reinterpret_cast<const float4*>(zb + dci * 32);
            z1[dci] = *reinterpret_cast<const float4*>(zb + dci * 32 + 4);
        }
    }

    for (int step = 0; step < BM / 16; ++step) {
        // ---- 1) cvt z -> B-frags (frees z regs); sz on wave 0 only ----
        bf16x8 zfrag[8];
#pragma unroll
        for (int dci = 0; dci < 8; ++dci) {
            float4 a = z0[dci], b = z1[dci];
            if (w == 0) {
                sz_run = fmaf(a.x, a.x, sz_run); sz_run = fmaf(a.y, a.y, sz_run);
                sz_run = fmaf(a.z, a.z, sz_run); sz_run = fmaf(a.w, a.w, sz_run);
                sz_run = fmaf(b.x, b.x, sz_run); sz_run = fmaf(b.y, b.y, sz_run);
                sz_run = fmaf(b.z, b.z, sz_run); sz_run = fmaf(b.w, b.w, sz_run);
            }
            us8 h;
            h[0] = bf16_rne(a.x); h[1] = bf16_rne(a.y); h[2] = bf16_rne(a.z); h[3] = bf16_rne(a.w);
            h[4] = bf16_rne(b.x); h[5] = bf16_rne(b.y); h[6] = bf16_rne(b.z); h[7] = bf16_rne(b.w);
            zfrag[dci] = __builtin_bit_cast(bf16x8, h);
        }
        // ---- 2) issue next step's z loads NOW (latency hides under 3+4) ----
        if (step < BM / 16 - 1) {
            const float* zb = ze + (m0 + (step + 1) * 16 + c) * DD + q * 8;
#pragma unroll
            for (int dci = 0; dci < 8; ++dci) {
                z0[dci] = *reinterpret_cast<const float4*>(zb + dci * 32);
                z1[dci] = *reinterpret_cast<const float4*>(zb + dci * 32 + 4);
            }
        }
        // ---- 3) MFMA (transposed): D[m=code][n=zrow] ----
        f32x4 acc[4];
#pragma unroll
        for (int mf = 0; mf < 4; ++mf) acc[mf] = (f32x4){0.f, 0.f, 0.f, 0.f};
#pragma unroll
        for (int dci = 0; dci < 8; ++dci)
#pragma unroll
            for (int mf = 0; mf < 4; ++mf)
                acc[mf] = __builtin_amdgcn_mfma_f32_16x16x32_bf16(cfr[mf][dci], zfrag[dci], acc[mf], 0, 0, 0);

        // ---- 4) LANE-LOCAL argmin: this lane holds 16 dists, ALL for z-row c ----
        //      code = 64w + 16mf + 4q + j; ascending (mf,j) = ascending code for fixed q
        float v1 = 3.4e38f, v2 = 3.4e38f; int k1 = 0x7fffffff;
#pragma unroll
        for (int mf = 0; mf < 4; ++mf)
#pragma unroll
            for (int j = 0; j < 4; ++j) {
                float dv = fmaf(-2.f, acc[mf][j], se_v[mf][j]);
                if (dv < v1) { v2 = v1; v1 = dv; k1 = 64 * w + 16 * mf + 4 * q + j; }
                else if (dv < v2) { v2 = dv; }
            }
        // merge across the 4 q-lanes holding the same row (xor 16, 32): 2 steps only
#pragma unroll
        for (int off = 16; off < 64; off <<= 1) {
            float ov1 = __shfl_xor(v1, off, 64);
            float ov2 = __shfl_xor(v2, off, 64);
            int   ok1 = __shfl_xor(k1, off, 64);
            bool other = (ov1 < v1) || (ov1 == v1 && ok1 < k1);
            float nv2 = other ? fminf(v1, ov2) : fminf(v2, ov1);
            if (other) { v1 = ov1; k1 = ok1; }
            v2 = nv2;
        }
        if ((t & 63) < 16) {   // q == 0 lanes: one per row
            int row = step * 16 + c;
            wv1[w * BM + row] = v1;
            wv2[w * BM + row] = v2;
            wk1[w * BM + row] = k1;
        }
    }
    __syncthreads();   // single post-loop barrier: all wv slices visible

    // ---- final merge: thread t (t<128) merges 4 wave-slices for row t ----
    float lossv = 0.f;
    if (t < BM) {
        float v1 = wv1[t], v2 = wv2[t]; int k1 = wk1[t];
#pragma unroll
        for (int ww = 1; ww < 4; ++ww) {
            float ov1 = wv1[ww * BM + t], ov2 = wv2[ww * BM + t];
            int ok1 = wk1[ww * BM + t];
            bool other = (ov1 < v1) || (ov1 == v1 && ok1 < k1);
            float nv2 = other ? fminf(v1, ov2) : fminf(v2, ov1);
            if (other) { v1 = ov1; k1 = ok1; }
            v2 = nv2;
        }
        out_inds[m0 + t] = (float)k1;
        lossv = v1;
        if (v2 - v1 < TAU) {
            int s_ = atomicAdd(gcnt, 1);
            if (s_ < FCAP) glist[s_] = (int)(m0 + t);
        }
    }
    __syncthreads();

    // ---- loss partial: sz (wave-0 lanes) + merged min-dists (t<128) ----
    red[t] = (w == 0 ? sz_run : 0.f) + (t < BM ? lossv : 0.f);
    __syncthreads();
    for (int s = 128; s > 0; s >>= 1) {
        if (t < s) red[t] += red[t + s];
        __syncthreads();
    }
    if (t == 0) atomicAdd(accum, (double)red[0]);
}

// ---------- deferred fix: bit-exact np fp32 pipeline, BATCHED 16 rows/group (r8-proven, inds only) ----------
__global__ __launch_bounds__(256)
void vq_fix(const float* __restrict__ ze, const float* __restrict__ emb,
            const float* __restrict__ se_g, const int* __restrict__ glist,
            const int* __restrict__ gcnt, float* __restrict__ out_inds)
{
    __shared__ float dq[16][256];
    __shared__ float srow_s[16];
    __shared__ int   rowid_s[16];

    const int t = threadIdx.x;
    int F = *gcnt; if (F > FCAP) F = FCAP;
    const float se_k = se_g[t];
    const float4* e4p = reinterpret_cast<const float4*>(emb + (size_t)t * DD);

    for (int g = blockIdx.x * 16; g < F; g += gridDim.x * 16) {
        __syncthreads();   // protect LDS reuse across iterations
        if (t < 16) {
            int idx = g + t; if (idx > F - 1) idx = F - 1;   // pad tail with dup of last
            int row = glist[idx];
            rowid_s[t] = row;
            srow_s[t] = np_sum256_sq(ze + (size_t)row * DD);
        }
        __syncthreads();

        // wave-uniform z-row pointers (scalar loads)
        const float* zp[16];
#pragma unroll
        for (int r = 0; r < 16; ++r)
            zp[r] = ze + (size_t)__builtin_amdgcn_readfirstlane(rowid_s[r]) * DD;

        // thread t emulates code k=t for all 16 rows: sequential 1-acc FMA over d
        float m32[16];
#pragma unroll
        for (int r = 0; r < 16; ++r) m32[r] = 0.f;
        for (int d4 = 0; d4 < 64; ++d4) {
            float4 e4 = e4p[d4];
            const int d = d4 * 4;
#pragma unroll
            for (int r = 0; r < 16; ++r) {
                m32[r] = __fmaf_rn(zp[r][d + 0], e4.x, m32[r]);
                m32[r] = __fmaf_rn(zp[r][d + 1], e4.y, m32[r]);
                m32[r] = __fmaf_rn(zp[r][d + 2], e4.z, m32[r]);
                m32[r] = __fmaf_rn(zp[r][d + 3], e4.w, m32[r]);
            }
        }
#pragma unroll
        for (int r = 0; r < 16; ++r) {
            float A = __fadd_rn(srow_s[r], se_k);
            dq[r][t] = __fsub_rn(A, __fmul_rn(2.0f, m32[r]));
        }
        __syncthreads();

        // per-row argmin: 16 threads per row (r = t>>4, portion p = t&15)
        {
            const int r = t >> 4, p = t & 15;
            float bv = 3.4e38f; int bk = 0x7fffffff;
#pragma unroll
            for (int i = 0; i < 16; ++i) {
                int k = p * 16 + i;
                float v = dq[r][k];
                if (v < bv) { bv = v; bk = k; }   // strict <: lowest index in subset
            }
#pragma unroll
            for (int off = 1; off < 16; off <<= 1) {
                float ov = __shfl_xor(bv, off, 64);
                int   ok = __shfl_xor(bk, off, 64);
                if (ov < bv || (ov == bv && ok < bk)) { bv = ov; bk = ok; }
            }
            if (p == 0 && g + r < F) out_inds[rowid_s[r]] = (float)bk;
        }
        __syncthreads();
    }
}

// ---------- gather: z_q[row] = emb[inds[row]] — pure streaming-write kernel ----------
__global__ __launch_bounds__(256)
void vq_gather(const float* __restrict__ emb, const float* __restrict__ out_inds,
               float* __restrict__ out_zq)
{
    const int t = threadIdx.x;
    const int w = t >> 6, l = t & 63;
    const size_t m0 = (size_t)blockIdx.x * 128 + (size_t)w * 32;
#pragma unroll 8
    for (int r = 0; r < 32; ++r) {
        int k = (int)out_inds[m0 + r];
        float4 v = *reinterpret_cast<const float4*>(emb + (size_t)k * DD + l * 4);
        *reinterpret_cast<float4*>(out_zq + (m0 + r) * DD + l * 4) = v;
    }
}

// ---------- finalize: loss = (1 + 0.25) * mean((z - q)^2) ----------
__global__ void vq_fin(const double* __restrict__ accum, float* __restrict__ out_loss) {
    *out_loss = (float)(1.25 * (*accum) / ((double)NROWS * (double)DD));
}

extern "C" void kernel_launch(void* const* d_in, const int* in_sizes, int n_in,
                              void* d_out, int out_size, void* d_ws, size_t ws_size,
                              hipStream_t stream) {
    const float* ze  = (const float*)d_in[0];
    const float* emb = (const float*)d_in[1];
    float* out      = (float*)d_out;
    float* out_zq   = out;
    float* out_inds = out + (size_t)NROWS * DD;
    float* out_loss = out + (size_t)NROWS * DD + NROWS;

    double* accum = (double*)d_ws;                                   // @0, 8B
    int*    gcnt  = (int*)((char*)d_ws + 8);                         // @8, 4B
    float*  se    = (float*)((char*)d_ws + 256);                     // @256, 1KB
    int*    glist = (int*)((char*)d_ws + 4096);                      // @4K, 256KB
    unsigned short* ph = (unsigned short*)((char*)d_ws + 4096 + 262144);  // 128KB

    vq_prep<<<1, 256, 0, stream>>>(emb, se, accum, gcnt);
    vq_split<<<KC * DD / (256 * 4), 256, 0, stream>>>(emb, ph);
    vq_main<<<NROWS / BM, 256, 0, stream>>>(ze, ph, se, out_inds, accum, glist, gcnt);
    vq_fix<<<1024, 256, 0, stream>>>(ze, emb, se, glist, gcnt, out_inds);
    vq_gather<<<NROWS / 128, 256, 0, stream>>>(emb, out_inds, out_zq);
    vq_fin<<<1, 1, 0, stream>>>(accum, out_loss);
}

// Round 16
// 322.937 us; speedup vs baseline: 1.4257x; 1.4257x over previous
//
#include <hip/hip_runtime.h>

typedef __attribute__((ext_vector_type(8))) short bf16x8;
typedef __attribute__((ext_vector_type(4))) float f32x4;
typedef __attribute__((ext_vector_type(4))) unsigned short us4;
typedef __attribute__((ext_vector_type(8))) unsigned short us8;

#define NROWS 262144
#define KC 256
#define DD 256
#define BM 64        // rows per block, col-split: wave = 64 rows x 64 codes
#define TAU 1.5e-3f  // flag threshold: ~9 sigma of single-pass bf16 error + np fp32 rounding
#define FCAP 65536   // flag list capacity
#define ZSW 264      // z LDS row stride in halves (256 + 8 pad -> rotated banks)

// ===== bit-exact numpy emulation helpers (defeat -ffp-contract) =====
__device__ __forceinline__ float np_pw128_sq(const float* a) {
    float r[8];
#pragma unroll
    for (int j = 0; j < 8; ++j) r[j] = __fmul_rn(a[j], a[j]);
    for (int i = 8; i < 128; i += 8) {
#pragma unroll
        for (int j = 0; j < 8; ++j)
            r[j] = __fadd_rn(r[j], __fmul_rn(a[i + j], a[i + j]));
    }
    float t01 = __fadd_rn(r[0], r[1]), t23 = __fadd_rn(r[2], r[3]);
    float t45 = __fadd_rn(r[4], r[5]), t67 = __fadd_rn(r[6], r[7]);
    return __fadd_rn(__fadd_rn(t01, t23), __fadd_rn(t45, t67));
}
__device__ __forceinline__ float np_sum256_sq(const float* a) {
    return __fadd_rn(np_pw128_sq(a), np_pw128_sq(a + 128));
}

// bf16 round-to-nearest-even
__device__ __forceinline__ unsigned short bf16_rne(float x) {
    unsigned b = __float_as_uint(x);
    b += 0x7FFFu + ((b >> 16) & 1u);
    return (unsigned short)(b >> 16);
}

// ---------- prep: se[k] = np-bit-exact sum(emb[k]^2); zero accum + flag count ----------
__global__ void vq_prep(const float* __restrict__ emb, float* __restrict__ se,
                        double* __restrict__ accum, int* __restrict__ gcnt) {
    int k = threadIdx.x;
    if (k == 0) { *accum = 0.0; *gcnt = 0; }
    se[k] = np_sum256_sq(emb + (size_t)k * DD);
}

// ---------- split emb -> FRAG-LINEAR bf16 plane ----------
// half-offset(k,d) = (d>>5)*8192 + (k>>4)*512 + (k&15)*32 + ((d>>3)&3)*8 + (d&7)
// so lane (c,q) of frag (dci, nf) reads a contiguous us8, and the whole wave reads 1KB linear.
__global__ void vq_split(const float* __restrict__ emb, unsigned short* __restrict__ ph) {
    int f = (blockIdx.x * 256 + threadIdx.x) * 4;   // element index (4 consecutive d)
    float4 v = *reinterpret_cast<const float4*>(emb + f);
    int k = f >> 8, d = f & 255;
    int off = (d >> 5) * 8192 + (k >> 4) * 512 + (k & 15) * 32 + ((d >> 3) & 3) * 8 + (d & 7);
    us4 h;
    h[0] = bf16_rne(v.x); h[1] = bf16_rne(v.y);
    h[2] = bf16_rne(v.z); h[3] = bf16_rne(v.w);
    *reinterpret_cast<us4*>(ph + off) = h;
}

// ---------- main: whole-z-in-LDS (bf16), e-chunk dbuf, one barrier/chunk ----------
__global__ __launch_bounds__(256, 2)
void vq_main(const float* __restrict__ ze, const unsigned short* __restrict__ ph,
             const float* __restrict__ se_g, float* __restrict__ out_inds,
             double* __restrict__ accum, int* __restrict__ glist, int* __restrict__ gcnt)
{
    __shared__ __attribute__((aligned(16))) unsigned short zl[BM * ZSW];   // 33.8 KB bf16 z tile
    __shared__ __attribute__((aligned(16))) unsigned short eb[2][8192];    // 2 x 16 KB e chunks
    __shared__ float se_s[KC];
    __shared__ float wv1[4 * BM], wv2[4 * BM];
    __shared__ int   wk1[4 * BM];
    __shared__ float red[256];

    const int t = threadIdx.x;
    const int w = t >> 6;          // wave: codes [64w, 64w+64)
    const int q = (t >> 4) & 3;    // k-quad within frag
    const int c = t & 15;          // row/col within frag
    const size_t m0 = (size_t)blockIdx.x * BM;

    se_s[t] = se_g[t];

    // ---- stage z: 16 fully-coalesced row-burst loads (wave = 1KB row per instr) ----
    float4 zr[16];
#pragma unroll
    for (int it = 0; it < 16; ++it) {
        int idx = it * 256 + t;            // float4 index in 64x256 tile
        int row = idx >> 6, c4 = idx & 63;
        zr[it] = *reinterpret_cast<const float4*>(ze + (m0 + row) * DD + c4 * 4);
    }
    float sz_acc = 0.f;
#pragma unroll
    for (int it = 0; it < 16; ++it) {
        float4 v = zr[it];
        int idx = it * 256 + t;
        int row = idx >> 6, c4 = idx & 63;
        sz_acc = fmaf(v.x, v.x, sz_acc); sz_acc = fmaf(v.y, v.y, sz_acc);
        sz_acc = fmaf(v.z, v.z, sz_acc); sz_acc = fmaf(v.w, v.w, sz_acc);
        us4 h;
        h[0] = bf16_rne(v.x); h[1] = bf16_rne(v.y);
        h[2] = bf16_rne(v.z); h[3] = bf16_rne(v.w);
        *reinterpret_cast<us4*>(&zl[row * ZSW + c4 * 4]) = h;
    }

    // ---- stage e chunk 0 (coalesced copy from frag-linear plane) ----
    us8 er[4];
#pragma unroll
    for (int i = 0; i < 4; ++i)
        er[i] = *reinterpret_cast<const us8*>(ph + (i * 256 + t) * 8);
#pragma unroll
    for (int i = 0; i < 4; ++i)
        *reinterpret_cast<us8*>(&eb[0][(i * 256 + t) * 8]) = er[i];
    __syncthreads();   // z, se, e0 all visible

    f32x4 acc[4][4];   // [mf][nf]
#pragma unroll
    for (int i = 0; i < 4; ++i)
#pragma unroll
        for (int j = 0; j < 4; ++j) acc[i][j] = (f32x4){0.f, 0.f, 0.f, 0.f};

    // ---- K-loop: 8 chunks, ONE barrier each; e(i+1) copy hides under MFMA(i) ----
#pragma unroll
    for (int dci = 0; dci < 8; ++dci) {
        const int cur = dci & 1;
        if (dci < 7) {
            const unsigned short* src = ph + (dci + 1) * 8192;
#pragma unroll
            for (int i = 0; i < 4; ++i)
                er[i] = *reinterpret_cast<const us8*>(src + (i * 256 + t) * 8);
        }
        bf16x8 af[4];
#pragma unroll
        for (int mf = 0; mf < 4; ++mf)
            af[mf] = *reinterpret_cast<const bf16x8*>(&zl[(16 * mf + c) * ZSW + dci * 32 + q * 8]);
#pragma unroll
        for (int nf = 0; nf < 4; ++nf) {
            bf16x8 bf = *reinterpret_cast<const bf16x8*>(&eb[cur][((4 * w + nf) * 64 + c * 4 + q) * 8]);
#pragma unroll
            for (int mf = 0; mf < 4; ++mf)
                acc[mf][nf] = __builtin_amdgcn_mfma_f32_16x16x32_bf16(af[mf], bf, acc[mf][nf], 0, 0, 0);
        }
        if (dci < 7) {
#pragma unroll
            for (int i = 0; i < 4; ++i)
                *reinterpret_cast<us8*>(&eb[cur ^ 1][(i * 256 + t) * 8]) = er[i];
        }
        __syncthreads();
    }

    // ---- per-row argmin over this wave's 64-code slice (r5-r7 proven epilogue) ----
#pragma unroll
    for (int mf = 0; mf < 4; ++mf)
#pragma unroll
        for (int j = 0; j < 4; ++j) {
            float v1 = 3.4e38f, v2 = 3.4e38f; int k1 = 0x7fffffff;
#pragma unroll
            for (int nf = 0; nf < 4; ++nf) {
                int k = 64 * w + 16 * nf + c;
                float dv = fmaf(-2.f, acc[mf][nf][j], se_s[k]);
                if (dv < v1) { v2 = v1; v1 = dv; k1 = k; }
                else if (dv < v2) { v2 = dv; }
            }
#pragma unroll
            for (int off = 1; off < 16; off <<= 1) {
                float ov1 = __shfl_xor(v1, off, 64);
                float ov2 = __shfl_xor(v2, off, 64);
                int   ok1 = __shfl_xor(k1, off, 64);
                bool other = (ov1 < v1) || (ov1 == v1 && ok1 < k1);
                float nv2 = other ? fminf(v1, ov2) : fminf(v2, ov1);
                if (other) { v1 = ov1; k1 = ok1; }
                v2 = nv2;
            }
            if (c == 0) {
                int row = 16 * mf + 4 * q + j;
                wv1[w * BM + row] = v1; wv2[w * BM + row] = v2; wk1[w * BM + row] = k1;
            }
        }
    __syncthreads();

    // ---- cross-wave merge (t<64), write inds, flag near-ties ----
    float lossv = 0.f;
    if (t < BM) {
        float v1 = wv1[t], v2 = wv2[t]; int k1 = wk1[t];
#pragma unroll
        for (int ww = 1; ww < 4; ++ww) {
            float ov1 = wv1[ww * BM + t], ov2 = wv2[ww * BM + t];
            int ok1 = wk1[ww * BM + t];
            bool other = (ov1 < v1) || (ov1 == v1 && ok1 < k1);
            float nv2 = other ? fminf(v1, ov2) : fminf(v2, ov1);
            if (other) { v1 = ov1; k1 = ok1; }
            v2 = nv2;
        }
        out_inds[m0 + t] = (float)k1;
        lossv = v1;
        if (v2 - v1 < TAU) {
            int s_ = atomicAdd(gcnt, 1);
            if (s_ < FCAP) glist[s_] = (int)(m0 + t);
        }
    }
    __syncthreads();

    // ---- loss partial ----
    red[t] = sz_acc + (t < BM ? lossv : 0.f);
    __syncthreads();
    for (int s = 128; s > 0; s >>= 1) {
        if (t < s) red[t] += red[t + s];
        __syncthreads();
    }
    if (t == 0) atomicAdd(accum, (double)red[0]);
}

// ---------- deferred fix: bit-exact np fp32 pipeline, BATCHED 16 rows/group (r13-proven) ----------
__global__ __launch_bounds__(256)
void vq_fix(const float* __restrict__ ze, const float* __restrict__ emb,
            const float* __restrict__ se_g, const int* __restrict__ glist,
            const int* __restrict__ gcnt, float* __restrict__ out_inds)
{
    __shared__ float dq[16][256];
    __shared__ float srow_s[16];
    __shared__ int   rowid_s[16];

    const int t = threadIdx.x;
    int F = *gcnt; if (F > FCAP) F = FCAP;
    const float se_k = se_g[t];
    const float4* e4p = reinterpret_cast<const float4*>(emb + (size_t)t * DD);

    for (int g = blockIdx.x * 16; g < F; g += gridDim.x * 16) {
        __syncthreads();   // protect LDS reuse across iterations
        if (t < 16) {
            int idx = g + t; if (idx > F - 1) idx = F - 1;   // pad tail with dup of last
            int row = glist[idx];
            rowid_s[t] = row;
            srow_s[t] = np_sum256_sq(ze + (size_t)row * DD);
        }
        __syncthreads();

        // wave-uniform z-row pointers (scalar loads)
        const float* zp[16];
#pragma unroll
        for (int r = 0; r < 16; ++r)
            zp[r] = ze + (size_t)__builtin_amdgcn_readfirstlane(rowid_s[r]) * DD;

        // thread t emulates code k=t for all 16 rows: sequential 1-acc FMA over d
        float m32[16];
#pragma unroll
        for (int r = 0; r < 16; ++r) m32[r] = 0.f;
        for (int d4 = 0; d4 < 64; ++d4) {
            float4 e4 = e4p[d4];
            const int d = d4 * 4;
#pragma unroll
            for (int r = 0; r < 16; ++r) {
                m32[r] = __fmaf_rn(zp[r][d + 0], e4.x, m32[r]);
                m32[r] = __fmaf_rn(zp[r][d + 1], e4.y, m32[r]);
                m32[r] = __fmaf_rn(zp[r][d + 2], e4.z, m32[r]);
                m32[r] = __fmaf_rn(zp[r][d + 3], e4.w, m32[r]);
            }
        }
#pragma unroll
        for (int r = 0; r < 16; ++r) {
            float A = __fadd_rn(srow_s[r], se_k);
            dq[r][t] = __fsub_rn(A, __fmul_rn(2.0f, m32[r]));
        }
        __syncthreads();

        // per-row argmin: 16 threads per row (r = t>>4, portion p = t&15)
        {
            const int r = t >> 4, p = t & 15;
            float bv = 3.4e38f; int bk = 0x7fffffff;
#pragma unroll
            for (int i = 0; i < 16; ++i) {
                int k = p * 16 + i;
                float v = dq[r][k];
                if (v < bv) { bv = v; bk = k; }   // strict <: lowest index in subset
            }
#pragma unroll
            for (int off = 1; off < 16; off <<= 1) {
                float ov = __shfl_xor(bv, off, 64);
                int   ok = __shfl_xor(bk, off, 64);
                if (ov < bv || (ov == bv && ok < bk)) { bv = ov; bk = ok; }
            }
            if (p == 0 && g + r < F) out_inds[rowid_s[r]] = (float)bk;
        }
        __syncthreads();
    }
}

// ---------- gather: z_q[row] = emb[inds[row]] — pure streaming-write kernel ----------
__global__ __launch_bounds__(256)
void vq_gather(const float* __restrict__ emb, const float* __restrict__ out_inds,
               float* __restrict__ out_zq)
{
    const int t = threadIdx.x;
    const int w = t >> 6, l = t & 63;
    const size_t m0 = (size_t)blockIdx.x * 128 + (size_t)w * 32;
#pragma unroll 8
    for (int r = 0; r < 32; ++r) {
        int k = (int)out_inds[m0 + r];
        float4 v = *reinterpret_cast<const float4*>(emb + (size_t)k * DD + l * 4);
        *reinterpret_cast<float4*>(out_zq + (m0 + r) * DD + l * 4) = v;
    }
}

// ---------- finalize: loss = (1 + 0.25) * mean((z - q)^2) ----------
__global__ void vq_fin(const double* __restrict__ accum, float* __restrict__ out_loss) {
    *out_loss = (float)(1.25 * (*accum) / ((double)NROWS * (double)DD));
}

extern "C" void kernel_launch(void* const* d_in, const int* in_sizes, int n_in,
                              void* d_out, int out_size, void* d_ws, size_t ws_size,
                              hipStream_t stream) {
    const float* ze  = (const float*)d_in[0];
    const float* emb = (const float*)d_in[1];
    float* out      = (float*)d_out;
    float* out_zq   = out;
    float* out_inds = out + (size_t)NROWS * DD;
    float* out_loss = out + (size_t)NROWS * DD + NROWS;

    double* accum = (double*)d_ws;                                   // @0, 8B
    int*    gcnt  = (int*)((char*)d_ws + 8);                         // @8, 4B
    float*  se    = (float*)((char*)d_ws + 256);                     // @256, 1KB
    int*    glist = (int*)((char*)d_ws + 4096);                      // @4K, 256KB
    unsigned short* ph = (unsigned short*)((char*)d_ws + 4096 + 262144);  // 128KB frag-linear plane

    vq_prep<<<1, 256, 0, stream>>>(emb, se, accum, gcnt);
    vq_split<<<KC * DD / (256 * 4), 256, 0, stream>>>(emb, ph);
    vq_main<<<NROWS / BM, 256, 0, stream>>>(ze, ph, se, out_inds, accum, glist, gcnt);
    vq_fix<<<1024, 256, 0, stream>>>(ze, emb, se, glist, gcnt, out_inds);
    vq_gather<<<NROWS / 128, 256, 0, stream>>>(emb, out_inds, out_zq);
    vq_fin<<<1, 1, 0, stream>>>(accum, out_loss);
}